// Round 5
// baseline (4273.125 us; speedup 1.0000x reference)
//
#include <hip/hip_runtime.h>
#include <hip/hip_bf16.h>
#include <stdint.h>

typedef __bf16 bf16x8 __attribute__((ext_vector_type(8)));
typedef float f32x4 __attribute__((ext_vector_type(4)));
typedef short short8 __attribute__((ext_vector_type(8)));
typedef unsigned long long u64;

#define B_ 32
#define T_ 512
#define D_ 1024
#define NG 4096
#define L_ 3
#define HD 32            // rotating h step-buffer depth
#define HSLOT 32768      // ushorts per slot (32 batches x 1024 units)
#define NWG3 192
#define NSTEP 514

__device__ inline unsigned short f2bf(float f) {
  unsigned u = __float_as_uint(f);
  unsigned r = (u + 0x7fffu + ((u >> 16) & 1u)) >> 16;
  return (unsigned short)r;
}
__device__ inline float bf2f(unsigned short h) {
  return __uint_as_float(((unsigned)h) << 16);
}
__device__ __forceinline__ float sigm(float x) { return 1.f / (1.f + __expf(-x)); }
__device__ __forceinline__ float tanh_(float x) {
  float e2 = __expf(-2.f * fabsf(x));
  return copysignf((1.f - e2) / (1.f + e2), x);
}

// ---------------- f32 -> bf16 convert (vectorized) ----------------
__global__ __launch_bounds__(256) void k_conv(const float* __restrict__ in,
                                              unsigned short* __restrict__ out, int n8) {
  int i = blockIdx.x * 256 + threadIdx.x;
  if (i >= n8) return;
  const float4* p = (const float4*)(in) + (size_t)i * 2;
  float4 a = p[0], b = p[1];
  short8 o;
  o[0] = (short)f2bf(a.x); o[1] = (short)f2bf(a.y); o[2] = (short)f2bf(a.z); o[3] = (short)f2bf(a.w);
  o[4] = (short)f2bf(b.x); o[5] = (short)f2bf(b.y); o[6] = (short)f2bf(b.z); o[7] = (short)f2bf(b.w);
  *((short8*)out + i) = o;
}

// ---------------- transpose+convert weights: (L,K,N) f32 -> (L,N,K) bf16 ----------------
__global__ __launch_bounds__(256) void k_transw(const float* __restrict__ in,
                                                unsigned short* __restrict__ out) {
  __shared__ float Tt[32][33];
  int k0 = blockIdx.x * 32, n0 = blockIdx.y * 32, l = blockIdx.z;
  const float* ip = in + (size_t)l * D_ * NG;
  unsigned short* op = out + (size_t)l * NG * D_;
  int r = threadIdx.x >> 5, c = threadIdx.x & 31;
  for (int rr = r; rr < 32; rr += 8)
    Tt[rr][c] = ip[(size_t)(k0 + rr) * NG + n0 + c];
  __syncthreads();
  for (int rr = r; rr < 32; rr += 8)
    op[(size_t)(n0 + rr) * D_ + k0 + c] = f2bf(Tt[c][rr]);
}

// ---------------- input-path GEMM (layer 0 only): Z = X @ Wi0 ----------------
#define PAD 40
__global__ __launch_bounds__(256) void k_gemm_in(const unsigned short* __restrict__ X,
                                                 const unsigned short* __restrict__ WT,
                                                 unsigned short* __restrict__ Z) {
  __shared__ short Al[128 * PAD];
  __shared__ short Bl[128 * PAD];
  int bx = blockIdx.x;
  int m0 = (bx >> 5) * 128, n0 = (bx & 31) * 128;
  int tid = threadIdx.x, lane = tid & 63, wv = tid >> 6;
  int wm = (wv >> 1) * 64, wn = (wv & 1) * 64;
  int l15 = lane & 15, lh = lane >> 4;
  f32x4 acc[4][4] = {};
  for (int s = 0; s < 32; ++s) {
    int k0 = s * 32;
    __syncthreads();
    for (int rr = 0; rr < 2; ++rr) {
      int ch = rr * 256 + tid;
      int row = ch >> 2, ko = (ch & 3) * 8;
      *(short8*)&Al[row * PAD + ko] = *(const short8*)&X[(size_t)(m0 + row) * 1024 + k0 + ko];
      *(short8*)&Bl[row * PAD + ko] = *(const short8*)&WT[(size_t)(n0 + row) * 1024 + k0 + ko];
    }
    __syncthreads();
    bf16x8 af[4], bfr[4];
    for (int mi = 0; mi < 4; ++mi)
      af[mi] = *(const bf16x8*)&Al[(wm + mi * 16 + l15) * PAD + lh * 8];
    for (int ni = 0; ni < 4; ++ni)
      bfr[ni] = *(const bf16x8*)&Bl[(wn + ni * 16 + l15) * PAD + lh * 8];
    for (int mi = 0; mi < 4; ++mi)
      for (int ni = 0; ni < 4; ++ni)
        acc[mi][ni] = __builtin_amdgcn_mfma_f32_16x16x32_bf16(af[mi], bfr[ni], acc[mi][ni], 0, 0, 0);
  }
  for (int mi = 0; mi < 4; ++mi)
    for (int ni = 0; ni < 4; ++ni)
      for (int r2 = 0; r2 < 4; ++r2) {
        int row = m0 + wm + mi * 16 + (lane >> 4) * 4 + r2;
        int col = n0 + wn + ni * 16 + l15;
        Z[(size_t)row * NG + col] = f2bf(acc[mi][ni][r2]);
      }
}

// ---------------- fused wavefronted 3-layer persistent recurrent kernel ----------------
// 192 WGs x 512 threads. WGs [0,64): layer0, [64,128): layer1, [128,192): layer2.
// Global step s: layer l computes t = s - l. Single flag barrier per step.
// Weight B-fragments pinned in VGPRs via per-step keep-alive asm ("+v") —
// round-4's VGPR_Count=108 proved the compiler sank them into the loop.
// h-ring slot 31 is pre-zeroed each launch so the t==0 recurrent MFMA reads
// legitimate zeros (no conditional 'dom' use that triggers spill heuristics).
template<int LAY>
__device__ __forceinline__ void rec_body(
    const unsigned short* __restrict__ WiL, const unsigned short* __restrict__ WhL,
    const unsigned short* __restrict__ Zin0, const float* __restrict__ biasL,
    unsigned short* __restrict__ hh, unsigned int* __restrict__ flags,
    float* __restrict__ yout, float* __restrict__ hT, float* __restrict__ cT,
    int wgl, float* zsb) {
  int tid = threadIdx.x, lane = tid & 63, kw = tid >> 6;
  int l15 = lane & 15, lh = lane >> 4;
  int U = wgl * 16;
  constexpr int NKF = (LAY == 0) ? 4 : 8;   // K-frags per wave (kspan = NKF*32)

  // ---- load this wave's weight B-fragments into VGPRs (once) ----
  bf16x8 bw[4 * NKF];
  {
    const unsigned short* Wsrc;
    int k0;
    if (LAY == 0) { Wsrc = WhL; k0 = kw * 128; }
    else { Wsrc = (kw < 4) ? WiL : WhL; k0 = (kw & 3) * 256; }
#pragma unroll
    for (int nt = 0; nt < 4; ++nt)
#pragma unroll
      for (int kf = 0; kf < NKF; ++kf)
        bw[nt * NKF + kf] =
            *(const bf16x8*)&Wsrc[(size_t)(nt * 1024 + U + l15) * 1024 + k0 + kf * 32 + lh * 8];
  }

  // elementwise cell: thread -> (batch b, unit j)
  int b = tid >> 4, j = tid & 15;
  int u = U + j;
  float bz0 = biasL[u], bz1 = biasL[1024 + u], bz2 = biasL[2048 + u], bz3 = biasL[3072 + u];
  float cst = 0.f;
  unsigned short* hhme = hh + (size_t)LAY * HD * HSLOT;
  const unsigned short* hhin = (LAY == 0) ? hhme : hh + (size_t)(LAY - 1) * HD * HSLOT;

  for (int s = 0; s < NSTEP; ++s) {
    int t = s - LAY;
    bool active = (t >= 0) && (t < T_);
    // ---- keep-alive pin: weight fragments must stay VGPR-resident ----
#pragma unroll
    for (int i = 0; i < 4 * NKF; ++i) asm volatile("" : "+v"(bw[i]));
    // ---- Zin prefetch (layer 0 only; independent of barrier) ----
    unsigned short zv0 = 0, zv1 = 0, zv2 = 0, zv3 = 0;
    if (LAY == 0 && active) {
      const unsigned short* zr = Zin0 + (size_t)(b * T_ + t) * NG + u;
      zv0 = zr[0]; zv1 = zr[1024]; zv2 = zr[2048]; zv3 = zr[3072];
    }
    // ---- global barrier: all 192 WGs finished step s-1 ----
    if (s > 0) {
      if (kw == 0) {
        const unsigned* fl = flags + (lane < 48 ? lane : 47) * 4;
        unsigned ss = (unsigned)s;
        for (;;) {
          unsigned f0 = __hip_atomic_load(fl + 0, __ATOMIC_RELAXED, __HIP_MEMORY_SCOPE_AGENT);
          unsigned f1 = __hip_atomic_load(fl + 1, __ATOMIC_RELAXED, __HIP_MEMORY_SCOPE_AGENT);
          unsigned f2 = __hip_atomic_load(fl + 2, __ATOMIC_RELAXED, __HIP_MEMORY_SCOPE_AGENT);
          unsigned f3 = __hip_atomic_load(fl + 3, __ATOMIC_RELAXED, __HIP_MEMORY_SCOPE_AGENT);
          bool ok = (lane >= 48) || ((f0 >= ss) & (f1 >= ss) & (f2 >= ss) & (f3 >= ss));
          if (__all(ok)) break;
          __builtin_amdgcn_s_sleep(1);
        }
        if ((s & (HD - 1)) == 0)
          __builtin_amdgcn_fence(__ATOMIC_ACQUIRE, "agent");  // clear caches before slot reuse
      }
      __syncthreads();
    }
    if (active) {
      // ---- GEMM: this wave's K-slice (unconditional; slot31 zeroed for t==0) ----
      const unsigned short* hsrc;
      if (LAY == 0)      hsrc = hhme + (size_t)((t - 1) & (HD - 1)) * HSLOT;
      else if (kw < 4)   hsrc = hhin + (size_t)(t & (HD - 1)) * HSLOT;
      else               hsrc = hhme + (size_t)((t - 1) & (HD - 1)) * HSLOT;
      f32x4 acc[2][4] = {};
#pragma unroll
      for (int kf = 0; kf < NKF; ++kf) {
        int k = (LAY == 0 ? kw * 128 : (kw & 3) * 256) + kf * 32 + lh * 8;
        const unsigned short* pa = hsrc + (k >> 2) * 128;
        u64 x0 = *(const u64*)(pa + l15 * 4);
        u64 x1 = *(const u64*)(pa + 128 + l15 * 4);
        u64 x2 = *(const u64*)(pa + 64 + l15 * 4);
        u64 x3 = *(const u64*)(pa + 192 + l15 * 4);
        bf16x8 a0, a1;
        ((u64*)&a0)[0] = x0; ((u64*)&a0)[1] = x1;
        ((u64*)&a1)[0] = x2; ((u64*)&a1)[1] = x3;
#pragma unroll
        for (int nt = 0; nt < 4; ++nt) {
          acc[0][nt] = __builtin_amdgcn_mfma_f32_16x16x32_bf16(a0, bw[nt * NKF + kf], acc[0][nt], 0, 0, 0);
          acc[1][nt] = __builtin_amdgcn_mfma_f32_16x16x32_bf16(a1, bw[nt * NKF + kf], acc[1][nt], 0, 0, 0);
        }
      }
      // ---- write split-K partials: zs[kw][mt*4+nt][lane][4] ----
#pragma unroll
      for (int mt = 0; mt < 2; ++mt)
#pragma unroll
        for (int nt = 0; nt < 4; ++nt)
          *(f32x4*)&zsb[(((kw * 8) + mt * 4 + nt) * 64 + lane) * 4] = acc[mt][nt];
    }
    __syncthreads();
    if (active) {
      // ---- reduce 8 partials + gates + state update ----
      int mt = b >> 4, lzs = ((b & 15) >> 2) * 16 + j, r = b & 3;
      float z0 = bz0, z1 = bz1, z2 = bz2, z3 = bz3;
#pragma unroll
      for (int k2 = 0; k2 < 8; ++k2) {
        int base = ((k2 * 8 + mt * 4) * 64 + lzs) * 4 + r;
        z0 += zsb[base];
        z1 += zsb[base + 256];
        z2 += zsb[base + 512];
        z3 += zsb[base + 768];
      }
      if (LAY == 0) { z0 += bf2f(zv0); z1 += bf2f(zv1); z2 += bf2f(zv2); z3 += bf2f(zv3); }
      float ig = sigm(z0), fg = sigm(z1), gg = tanh_(z2), og = sigm(z3);
      cst = fg * cst + ig * gg;
      float hv = og * tanh_(cst);
      unsigned short hw = f2bf(hv);
      unsigned short* ha = hhme + (size_t)(t & (HD - 1)) * HSLOT + (u >> 2) * 128 + b * 4 + (u & 3);
      unsigned hw32 = hw;
      asm volatile("global_store_short %0, %1, off sc0 sc1" :: "v"(ha), "v"(hw32) : "memory");
      if (LAY == 2) __builtin_nontemporal_store(hv, &yout[(size_t)(b * T_ + t) * 1024 + u]);
      if (t == T_ - 1) {
        hT[LAY * (B_ * 1024) + b * 1024 + u] = hv;
        cT[LAY * (B_ * 1024) + b * 1024 + u] = cst;
      }
    }
    // drain asm h-stores before signaling (per-wave), then WG-join, then flag
    asm volatile("s_waitcnt vmcnt(0)" ::: "memory");
    __syncthreads();
    if (tid == 0 && s < NSTEP - 1)
      __hip_atomic_store(&flags[blockIdx.x], (unsigned)(s + 1), __ATOMIC_RELAXED, __HIP_MEMORY_SCOPE_AGENT);
  }
}

__global__ __launch_bounds__(512, 1) void k_rec3(
    const unsigned short* __restrict__ WiT, const unsigned short* __restrict__ WhT,
    const unsigned short* __restrict__ Zin0, const float* __restrict__ bias,
    unsigned short* __restrict__ hh, unsigned int* __restrict__ flags,
    float* __restrict__ yout, float* __restrict__ hT, float* __restrict__ cT) {
  extern __shared__ float zsb[];   // 64KB: [kw][8][64][4] f32
  int wg = blockIdx.x;
  int lay = (wg >= 64) + (wg >= 128);
  int wgl = wg & 63;
  const unsigned short* WiL = WiT + (size_t)lay * NG * 1024;
  const unsigned short* WhL = WhT + (size_t)lay * NG * 1024;
  const float* biasL = bias + lay * NG;
  if (lay == 0)      rec_body<0>(WiL, WhL, Zin0, biasL, hh, flags, yout, hT, cT, wgl, zsb);
  else if (lay == 1) rec_body<1>(WiL, WhL, Zin0, biasL, hh, flags, yout, hT, cT, wgl, zsb);
  else               rec_body<2>(WiL, WhL, Zin0, biasL, hh, flags, yout, hT, cT, wgl, zsb);
}

extern "C" void kernel_launch(void* const* d_in, const int* in_sizes, int n_in,
                              void* d_out, int out_size, void* d_ws, size_t ws_size,
                              hipStream_t stream) {
  const float* x = (const float*)d_in[0];
  const float* Wi = (const float*)d_in[1];
  const float* Wh = (const float*)d_in[2];
  const float* bias = (const float*)d_in[3];
  float* out = (float*)d_out;
  uint8_t* W = (uint8_t*)d_ws;

  unsigned* flags = (unsigned*)W;                                   // 192 flags
  unsigned short* hh  = (unsigned short*)(W + 0x10000);             // 3 x 32 x 64KB = 6MB
  unsigned short* Zin0 = (unsigned short*)(W + 0x800000);           // 128MB bf16 (B*T,4096)
  unsigned short* Xa  = (unsigned short*)(W + 0x8800000);           // 32MB bf16 (B*T,1024)
  unsigned short* WiT = (unsigned short*)(W + 0xA800000);           // 24MB bf16 (L,4096,1024)
  unsigned short* WhT = (unsigned short*)(W + 0xC000000);           // 24MB (ends 0xD800000)

  hipMemsetAsync(d_ws, 0, 4096, stream);                            // flags
  // zero slot 31 of each layer's h-ring (read as h(-1)=0 at t==0)
  hipMemsetAsync(W + 0x10000 + (size_t)31 * 65536, 0, 65536, stream);
  hipMemsetAsync(W + 0x10000 + (size_t)63 * 65536, 0, 65536, stream);
  hipMemsetAsync(W + 0x10000 + (size_t)95 * 65536, 0, 65536, stream);
  k_conv<<<8192, 256, 0, stream>>>(x, Xa, (B_ * T_ * D_) / 8);
  k_transw<<<dim3(32, 128, 3), 256, 0, stream>>>(Wi, WiT);
  k_transw<<<dim3(32, 128, 3), 256, 0, stream>>>(Wh, WhT);
  k_gemm_in<<<4096, 256, 0, stream>>>(Xa, WiT, Zin0);   // layer 0 input gates

  float* yout = out;
  float* hT = out + 16777216;
  float* cT = out + 16777216 + 98304;
  k_rec3<<<NWG3, 512, 65536, stream>>>(WiT, WhT, Zin0, bias, hh, flags, yout, hT, cT);
}

// Round 6
// 4075.364 us; speedup vs baseline: 1.0485x; 1.0485x over previous
//
#include <hip/hip_runtime.h>
#include <hip/hip_bf16.h>
#include <stdint.h>

typedef __bf16 bf16x8 __attribute__((ext_vector_type(8)));
typedef float f32x4 __attribute__((ext_vector_type(4)));
typedef short short8 __attribute__((ext_vector_type(8)));
typedef unsigned long long u64;

#define B_ 32
#define T_ 512
#define D_ 1024
#define NG 4096
#define L_ 3
#define HD 32            // rotating h step-buffer depth
#define HSLOT 32768      // ushorts per slot (32 batches x 1024 units)
#define NWG3 192
#define NSTEP 514

__device__ inline unsigned short f2bf(float f) {
  unsigned u = __float_as_uint(f);
  unsigned r = (u + 0x7fffu + ((u >> 16) & 1u)) >> 16;
  return (unsigned short)r;
}
__device__ inline float bf2f(unsigned short h) {
  return __uint_as_float(((unsigned)h) << 16);
}
__device__ __forceinline__ float sigm(float x) { return 1.f / (1.f + __expf(-x)); }
__device__ __forceinline__ float tanh_(float x) {
  float e2 = __expf(-2.f * fabsf(x));
  return copysignf((1.f - e2) / (1.f + e2), x);
}

// ---------------- f32 -> bf16 convert (vectorized) ----------------
__global__ __launch_bounds__(256) void k_conv(const float* __restrict__ in,
                                              unsigned short* __restrict__ out, int n8) {
  int i = blockIdx.x * 256 + threadIdx.x;
  if (i >= n8) return;
  const float4* p = (const float4*)(in) + (size_t)i * 2;
  float4 a = p[0], b = p[1];
  short8 o;
  o[0] = (short)f2bf(a.x); o[1] = (short)f2bf(a.y); o[2] = (short)f2bf(a.z); o[3] = (short)f2bf(a.w);
  o[4] = (short)f2bf(b.x); o[5] = (short)f2bf(b.y); o[6] = (short)f2bf(b.z); o[7] = (short)f2bf(b.w);
  *((short8*)out + i) = o;
}

// ---------------- transpose+convert weights: (L,K,N) f32 -> (L,N,K) bf16 ----------------
__global__ __launch_bounds__(256) void k_transw(const float* __restrict__ in,
                                                unsigned short* __restrict__ out) {
  __shared__ float Tt[32][33];
  int k0 = blockIdx.x * 32, n0 = blockIdx.y * 32, l = blockIdx.z;
  const float* ip = in + (size_t)l * D_ * NG;
  unsigned short* op = out + (size_t)l * NG * D_;
  int r = threadIdx.x >> 5, c = threadIdx.x & 31;
  for (int rr = r; rr < 32; rr += 8)
    Tt[rr][c] = ip[(size_t)(k0 + rr) * NG + n0 + c];
  __syncthreads();
  for (int rr = r; rr < 32; rr += 8)
    op[(size_t)(n0 + rr) * D_ + k0 + c] = f2bf(Tt[c][rr]);
}

// ---------------- input-path GEMM (layer 0 only): Z = X @ Wi0 ----------------
#define PAD 40
__global__ __launch_bounds__(256) void k_gemm_in(const unsigned short* __restrict__ X,
                                                 const unsigned short* __restrict__ WT,
                                                 unsigned short* __restrict__ Z) {
  __shared__ short Al[128 * PAD];
  __shared__ short Bl[128 * PAD];
  int bx = blockIdx.x;
  int m0 = (bx >> 5) * 128, n0 = (bx & 31) * 128;
  int tid = threadIdx.x, lane = tid & 63, wv = tid >> 6;
  int wm = (wv >> 1) * 64, wn = (wv & 1) * 64;
  int l15 = lane & 15, lh = lane >> 4;
  f32x4 acc[4][4] = {};
  for (int s = 0; s < 32; ++s) {
    int k0 = s * 32;
    __syncthreads();
    for (int rr = 0; rr < 2; ++rr) {
      int ch = rr * 256 + tid;
      int row = ch >> 2, ko = (ch & 3) * 8;
      *(short8*)&Al[row * PAD + ko] = *(const short8*)&X[(size_t)(m0 + row) * 1024 + k0 + ko];
      *(short8*)&Bl[row * PAD + ko] = *(const short8*)&WT[(size_t)(n0 + row) * 1024 + k0 + ko];
    }
    __syncthreads();
    bf16x8 af[4], bfr[4];
    for (int mi = 0; mi < 4; ++mi)
      af[mi] = *(const bf16x8*)&Al[(wm + mi * 16 + l15) * PAD + lh * 8];
    for (int ni = 0; ni < 4; ++ni)
      bfr[ni] = *(const bf16x8*)&Bl[(wn + ni * 16 + l15) * PAD + lh * 8];
    for (int mi = 0; mi < 4; ++mi)
      for (int ni = 0; ni < 4; ++ni)
        acc[mi][ni] = __builtin_amdgcn_mfma_f32_16x16x32_bf16(af[mi], bfr[ni], acc[mi][ni], 0, 0, 0);
  }
  for (int mi = 0; mi < 4; ++mi)
    for (int ni = 0; ni < 4; ++ni)
      for (int r2 = 0; r2 < 4; ++r2) {
        int row = m0 + wm + mi * 16 + (lane >> 4) * 4 + r2;
        int col = n0 + wn + ni * 16 + l15;
        Z[(size_t)row * NG + col] = f2bf(acc[mi][ni][r2]);
      }
}

// ---------------- fused wavefronted 3-layer persistent recurrent kernel ----------------
// 192 WGs x 512 threads (8 waves = 2 waves/EU, 1 WG/CU). amdgpu_waves_per_eu(2,2)
// pins the allocator budget at 256 VGPR/wave so the 128 VGPRs of weight fragments
// stay register-resident (round-5 showed the default heuristic targets 4 waves/EU
// and remats the weight loads every step -> 48MB/step L2/MALL reload traffic).
// One-time opaque asm pin after the load defeats remat (volatile asm is
// non-duplicable); with a 256 budget there is no spill either.
template<int LAY>
__device__ __forceinline__ void rec_body(
    const unsigned short* __restrict__ WiL, const unsigned short* __restrict__ WhL,
    const unsigned short* __restrict__ Zin0, const float* __restrict__ biasL,
    unsigned short* __restrict__ hh, unsigned int* __restrict__ flags,
    float* __restrict__ yout, float* __restrict__ hT, float* __restrict__ cT,
    int wgl, float* zsb) {
  int tid = threadIdx.x, lane = tid & 63, kw = tid >> 6;
  int l15 = lane & 15, lh = lane >> 4;
  int U = wgl * 16;
  constexpr int NKF = (LAY == 0) ? 4 : 8;   // K-frags per wave (kspan = NKF*32)

  // ---- load this wave's weight B-fragments into VGPRs (once) ----
  bf16x8 bw[4 * NKF];
  {
    const unsigned short* Wsrc;
    int k0;
    if (LAY == 0) { Wsrc = WhL; k0 = kw * 128; }
    else { Wsrc = (kw < 4) ? WiL : WhL; k0 = (kw & 3) * 256; }
#pragma unroll
    for (int nt = 0; nt < 4; ++nt)
#pragma unroll
      for (int kf = 0; kf < NKF; ++kf)
        bw[nt * NKF + kf] =
            *(const bf16x8*)&Wsrc[(size_t)(nt * 1024 + U + l15) * 1024 + k0 + kf * 32 + lh * 8];
  }
  // one-time opaque pin: post-asm values are non-rematerializable
#pragma unroll
  for (int i = 0; i < 4 * NKF; ++i) asm volatile("" : "+v"(bw[i]));

  // elementwise cell: thread -> (batch b, unit j)
  int b = tid >> 4, j = tid & 15;
  int u = U + j;
  float bz0 = biasL[u], bz1 = biasL[1024 + u], bz2 = biasL[2048 + u], bz3 = biasL[3072 + u];
  float cst = 0.f;
  unsigned short* hhme = hh + (size_t)LAY * HD * HSLOT;
  const unsigned short* hhin = (LAY == 0) ? hhme : hh + (size_t)(LAY - 1) * HD * HSLOT;

  for (int s = 0; s < NSTEP; ++s) {
    int t = s - LAY;
    bool active = (t >= 0) && (t < T_);
    // ---- Zin prefetch (layer 0 only; independent of barrier) ----
    unsigned short zv0 = 0, zv1 = 0, zv2 = 0, zv3 = 0;
    if (LAY == 0 && active) {
      const unsigned short* zr = Zin0 + (size_t)(b * T_ + t) * NG + u;
      zv0 = zr[0]; zv1 = zr[1024]; zv2 = zr[2048]; zv3 = zr[3072];
    }
    // ---- global barrier: all 192 WGs finished step s-1 ----
    if (s > 0) {
      if (kw == 0) {
        const unsigned* fl = flags + (lane < 48 ? lane : 47) * 4;
        unsigned ss = (unsigned)s;
        for (;;) {
          unsigned f0 = __hip_atomic_load(fl + 0, __ATOMIC_RELAXED, __HIP_MEMORY_SCOPE_AGENT);
          unsigned f1 = __hip_atomic_load(fl + 1, __ATOMIC_RELAXED, __HIP_MEMORY_SCOPE_AGENT);
          unsigned f2 = __hip_atomic_load(fl + 2, __ATOMIC_RELAXED, __HIP_MEMORY_SCOPE_AGENT);
          unsigned f3 = __hip_atomic_load(fl + 3, __ATOMIC_RELAXED, __HIP_MEMORY_SCOPE_AGENT);
          bool ok = (lane >= 48) || ((f0 >= ss) & (f1 >= ss) & (f2 >= ss) & (f3 >= ss));
          if (__all(ok)) break;
          __builtin_amdgcn_s_sleep(1);
        }
        if ((s & (HD - 1)) == 0)
          __builtin_amdgcn_fence(__ATOMIC_ACQUIRE, "agent");  // clear caches before slot reuse
      }
      __syncthreads();
    }
    if (active) {
      // ---- GEMM: this wave's K-slice (unconditional; slot31 zeroed for t==0) ----
      const unsigned short* hsrc;
      if (LAY == 0)      hsrc = hhme + (size_t)((t - 1) & (HD - 1)) * HSLOT;
      else if (kw < 4)   hsrc = hhin + (size_t)(t & (HD - 1)) * HSLOT;
      else               hsrc = hhme + (size_t)((t - 1) & (HD - 1)) * HSLOT;
      f32x4 acc[2][4] = {};
#pragma unroll
      for (int kf = 0; kf < NKF; ++kf) {
        int k = (LAY == 0 ? kw * 128 : (kw & 3) * 256) + kf * 32 + lh * 8;
        const unsigned short* pa = hsrc + (k >> 2) * 128;
        u64 x0 = *(const u64*)(pa + l15 * 4);
        u64 x1 = *(const u64*)(pa + 128 + l15 * 4);
        u64 x2 = *(const u64*)(pa + 64 + l15 * 4);
        u64 x3 = *(const u64*)(pa + 192 + l15 * 4);
        bf16x8 a0, a1;
        ((u64*)&a0)[0] = x0; ((u64*)&a0)[1] = x1;
        ((u64*)&a1)[0] = x2; ((u64*)&a1)[1] = x3;
#pragma unroll
        for (int nt = 0; nt < 4; ++nt) {
          acc[0][nt] = __builtin_amdgcn_mfma_f32_16x16x32_bf16(a0, bw[nt * NKF + kf], acc[0][nt], 0, 0, 0);
          acc[1][nt] = __builtin_amdgcn_mfma_f32_16x16x32_bf16(a1, bw[nt * NKF + kf], acc[1][nt], 0, 0, 0);
        }
      }
      // ---- write split-K partials: zs[kw][mt*4+nt][lane][4] ----
#pragma unroll
      for (int mt = 0; mt < 2; ++mt)
#pragma unroll
        for (int nt = 0; nt < 4; ++nt)
          *(f32x4*)&zsb[(((kw * 8) + mt * 4 + nt) * 64 + lane) * 4] = acc[mt][nt];
    }
    __syncthreads();
    if (active) {
      // ---- reduce 8 partials + gates + state update ----
      int mt = b >> 4, lzs = ((b & 15) >> 2) * 16 + j, r = b & 3;
      float z0 = bz0, z1 = bz1, z2 = bz2, z3 = bz3;
#pragma unroll
      for (int k2 = 0; k2 < 8; ++k2) {
        int base = ((k2 * 8 + mt * 4) * 64 + lzs) * 4 + r;
        z0 += zsb[base];
        z1 += zsb[base + 256];
        z2 += zsb[base + 512];
        z3 += zsb[base + 768];
      }
      if (LAY == 0) { z0 += bf2f(zv0); z1 += bf2f(zv1); z2 += bf2f(zv2); z3 += bf2f(zv3); }
      float ig = sigm(z0), fg = sigm(z1), gg = tanh_(z2), og = sigm(z3);
      cst = fg * cst + ig * gg;
      float hv = og * tanh_(cst);
      unsigned short hw = f2bf(hv);
      unsigned short* ha = hhme + (size_t)(t & (HD - 1)) * HSLOT + (u >> 2) * 128 + b * 4 + (u & 3);
      unsigned hw32 = hw;
      asm volatile("global_store_short %0, %1, off sc0 sc1" :: "v"(ha), "v"(hw32) : "memory");
      if (LAY == 2) __builtin_nontemporal_store(hv, &yout[(size_t)(b * T_ + t) * 1024 + u]);
      if (t == T_ - 1) {
        hT[LAY * (B_ * 1024) + b * 1024 + u] = hv;
        cT[LAY * (B_ * 1024) + b * 1024 + u] = cst;
      }
    }
    // drain asm h-stores before signaling (per-wave), then WG-join, then flag
    asm volatile("s_waitcnt vmcnt(0)" ::: "memory");
    __syncthreads();
    if (tid == 0 && s < NSTEP - 1)
      __hip_atomic_store(&flags[blockIdx.x], (unsigned)(s + 1), __ATOMIC_RELAXED, __HIP_MEMORY_SCOPE_AGENT);
  }
}

__global__ __launch_bounds__(512)
__attribute__((amdgpu_waves_per_eu(2, 2)))
void k_rec3(
    const unsigned short* __restrict__ WiT, const unsigned short* __restrict__ WhT,
    const unsigned short* __restrict__ Zin0, const float* __restrict__ bias,
    unsigned short* __restrict__ hh, unsigned int* __restrict__ flags,
    float* __restrict__ yout, float* __restrict__ hT, float* __restrict__ cT) {
  extern __shared__ float zsb[];   // 64KB: [kw][8][64][4] f32
  int wg = blockIdx.x;
  int lay = (wg >= 64) + (wg >= 128);
  int wgl = wg & 63;
  const unsigned short* WiL = WiT + (size_t)lay * NG * 1024;
  const unsigned short* WhL = WhT + (size_t)lay * NG * 1024;
  const float* biasL = bias + lay * NG;
  if (lay == 0)      rec_body<0>(WiL, WhL, Zin0, biasL, hh, flags, yout, hT, cT, wgl, zsb);
  else if (lay == 1) rec_body<1>(WiL, WhL, Zin0, biasL, hh, flags, yout, hT, cT, wgl, zsb);
  else               rec_body<2>(WiL, WhL, Zin0, biasL, hh, flags, yout, hT, cT, wgl, zsb);
}

extern "C" void kernel_launch(void* const* d_in, const int* in_sizes, int n_in,
                              void* d_out, int out_size, void* d_ws, size_t ws_size,
                              hipStream_t stream) {
  const float* x = (const float*)d_in[0];
  const float* Wi = (const float*)d_in[1];
  const float* Wh = (const float*)d_in[2];
  const float* bias = (const float*)d_in[3];
  float* out = (float*)d_out;
  uint8_t* W = (uint8_t*)d_ws;

  unsigned* flags = (unsigned*)W;                                   // 192 flags
  unsigned short* hh  = (unsigned short*)(W + 0x10000);             // 3 x 32 x 64KB = 6MB
  unsigned short* Zin0 = (unsigned short*)(W + 0x800000);           // 128MB bf16 (B*T,4096)
  unsigned short* Xa  = (unsigned short*)(W + 0x8800000);           // 32MB bf16 (B*T,1024)
  unsigned short* WiT = (unsigned short*)(W + 0xA800000);           // 24MB bf16 (L,4096,1024)
  unsigned short* WhT = (unsigned short*)(W + 0xC000000);           // 24MB (ends 0xD800000)

  hipMemsetAsync(d_ws, 0, 4096, stream);                            // flags
  // zero slot 31 of each layer's h-ring (read as h(-1)=0 at t==0)
  hipMemsetAsync(W + 0x10000 + (size_t)31 * 65536, 0, 65536, stream);
  hipMemsetAsync(W + 0x10000 + (size_t)63 * 65536, 0, 65536, stream);
  hipMemsetAsync(W + 0x10000 + (size_t)95 * 65536, 0, 65536, stream);
  k_conv<<<8192, 256, 0, stream>>>(x, Xa, (B_ * T_ * D_) / 8);
  k_transw<<<dim3(32, 128, 3), 256, 0, stream>>>(Wi, WiT);
  k_transw<<<dim3(32, 128, 3), 256, 0, stream>>>(Wh, WhT);
  k_gemm_in<<<4096, 256, 0, stream>>>(Xa, WiT, Zin0);   // layer 0 input gates

  float* yout = out;
  float* hT = out + 16777216;
  float* cT = out + 16777216 + 98304;
  k_rec3<<<NWG3, 512, 65536, stream>>>(WiT, WhT, Zin0, bias, hh, flags, yout, hT, cT);
}

// Round 7
// 3694.880 us; speedup vs baseline: 1.1565x; 1.1030x over previous
//
#include <hip/hip_runtime.h>
#include <hip/hip_bf16.h>
#include <stdint.h>

typedef __bf16 bf16x8 __attribute__((ext_vector_type(8)));
typedef float f32x4 __attribute__((ext_vector_type(4)));
typedef short short8 __attribute__((ext_vector_type(8)));
typedef unsigned long long u64;

#define B_ 32
#define T_ 512
#define D_ 1024
#define NG 4096
#define L_ 3
#define HD 32            // rotating h step-buffer depth
#define HSLOT 32768      // ushorts per slot (32 batches x 1024 units)
#define NWG3 192
#define NSTEP 514

__device__ inline unsigned short f2bf(float f) {
  unsigned u = __float_as_uint(f);
  unsigned r = (u + 0x7fffu + ((u >> 16) & 1u)) >> 16;
  return (unsigned short)r;
}
__device__ inline float bf2f(unsigned short h) {
  return __uint_as_float(((unsigned)h) << 16);
}
__device__ __forceinline__ float sigm(float x) { return 1.f / (1.f + __expf(-x)); }
__device__ __forceinline__ float tanh_(float x) {
  float e2 = __expf(-2.f * fabsf(x));
  return copysignf((1.f - e2) / (1.f + e2), x);
}

// ---------------- f32 -> bf16 convert (vectorized) ----------------
__global__ __launch_bounds__(256) void k_conv(const float* __restrict__ in,
                                              unsigned short* __restrict__ out, int n8) {
  int i = blockIdx.x * 256 + threadIdx.x;
  if (i >= n8) return;
  const float4* p = (const float4*)(in) + (size_t)i * 2;
  float4 a = p[0], b = p[1];
  short8 o;
  o[0] = (short)f2bf(a.x); o[1] = (short)f2bf(a.y); o[2] = (short)f2bf(a.z); o[3] = (short)f2bf(a.w);
  o[4] = (short)f2bf(b.x); o[5] = (short)f2bf(b.y); o[6] = (short)f2bf(b.z); o[7] = (short)f2bf(b.w);
  *((short8*)out + i) = o;
}

// ---------------- transpose+convert weights: (L,K,N) f32 -> (L,N,K) bf16 ----------------
__global__ __launch_bounds__(256) void k_transw(const float* __restrict__ in,
                                                unsigned short* __restrict__ out) {
  __shared__ float Tt[32][33];
  int k0 = blockIdx.x * 32, n0 = blockIdx.y * 32, l = blockIdx.z;
  const float* ip = in + (size_t)l * D_ * NG;
  unsigned short* op = out + (size_t)l * NG * D_;
  int r = threadIdx.x >> 5, c = threadIdx.x & 31;
  for (int rr = r; rr < 32; rr += 8)
    Tt[rr][c] = ip[(size_t)(k0 + rr) * NG + n0 + c];
  __syncthreads();
  for (int rr = r; rr < 32; rr += 8)
    op[(size_t)(n0 + rr) * D_ + k0 + c] = f2bf(Tt[c][rr]);
}

// ---------------- input-path GEMM (layer 0 only): Z = X @ Wi0 ----------------
#define PAD 40
__global__ __launch_bounds__(256) void k_gemm_in(const unsigned short* __restrict__ X,
                                                 const unsigned short* __restrict__ WT,
                                                 unsigned short* __restrict__ Z) {
  __shared__ short Al[128 * PAD];
  __shared__ short Bl[128 * PAD];
  int bx = blockIdx.x;
  int m0 = (bx >> 5) * 128, n0 = (bx & 31) * 128;
  int tid = threadIdx.x, lane = tid & 63, wv = tid >> 6;
  int wm = (wv >> 1) * 64, wn = (wv & 1) * 64;
  int l15 = lane & 15, lh = lane >> 4;
  f32x4 acc[4][4] = {};
  for (int s = 0; s < 32; ++s) {
    int k0 = s * 32;
    __syncthreads();
    for (int rr = 0; rr < 2; ++rr) {
      int ch = rr * 256 + tid;
      int row = ch >> 2, ko = (ch & 3) * 8;
      *(short8*)&Al[row * PAD + ko] = *(const short8*)&X[(size_t)(m0 + row) * 1024 + k0 + ko];
      *(short8*)&Bl[row * PAD + ko] = *(const short8*)&WT[(size_t)(n0 + row) * 1024 + k0 + ko];
    }
    __syncthreads();
    bf16x8 af[4], bfr[4];
    for (int mi = 0; mi < 4; ++mi)
      af[mi] = *(const bf16x8*)&Al[(wm + mi * 16 + l15) * PAD + lh * 8];
    for (int ni = 0; ni < 4; ++ni)
      bfr[ni] = *(const bf16x8*)&Bl[(wn + ni * 16 + l15) * PAD + lh * 8];
    for (int mi = 0; mi < 4; ++mi)
      for (int ni = 0; ni < 4; ++ni)
        acc[mi][ni] = __builtin_amdgcn_mfma_f32_16x16x32_bf16(af[mi], bfr[ni], acc[mi][ni], 0, 0, 0);
  }
  for (int mi = 0; mi < 4; ++mi)
    for (int ni = 0; ni < 4; ++ni)
      for (int r2 = 0; r2 < 4; ++r2) {
        int row = m0 + wm + mi * 16 + (lane >> 4) * 4 + r2;
        int col = n0 + wn + ni * 16 + l15;
        Z[(size_t)row * NG + col] = f2bf(acc[mi][ni][r2]);
      }
}

// ---------------- fused wavefronted 3-layer persistent recurrent kernel ----------------
// Round-7 changes:
//  1. Per-layer dependency flags: layer l polls own 64 flags + layer(l-1)'s 64 flags
//     (>= s), plus back-pressure on layer(l+1) (>= s-24) protecting the 32-deep ring.
//     No more global 192-WG barrier; layers skew and absorb jitter.
//  2. Output stores (y, hT, cT) moved AFTER the flag signal — the per-step
//     vmcnt(0) drain now covers only the 2-byte h-store, not HBM store acks.
// Weight fragments live in AGPRs (unified RF; VGPR_Count=108 across rounds 4-6
// proved residency was never the issue). h exchange unchanged: rotating slots,
// sc0/sc1 write-through, relaxed flags, acquire fence every 32 steps.
template<int LAY>
__device__ __forceinline__ void rec_body(
    const unsigned short* __restrict__ WiL, const unsigned short* __restrict__ WhL,
    const unsigned short* __restrict__ Zin0, const float* __restrict__ biasL,
    unsigned short* __restrict__ hh, unsigned int* __restrict__ flags,
    float* __restrict__ yout, float* __restrict__ hT, float* __restrict__ cT,
    int wgl, float* zsb) {
  int tid = threadIdx.x, lane = tid & 63, kw = tid >> 6;
  int l15 = lane & 15, lh = lane >> 4;
  int U = wgl * 16;
  constexpr int NKF = (LAY == 0) ? 4 : 8;   // K-frags per wave (kspan = NKF*32)

  // ---- load this wave's weight B-fragments (AGPR/VGPR resident) ----
  bf16x8 bw[4 * NKF];
  {
    const unsigned short* Wsrc;
    int k0;
    if (LAY == 0) { Wsrc = WhL; k0 = kw * 128; }
    else { Wsrc = (kw < 4) ? WiL : WhL; k0 = (kw & 3) * 256; }
#pragma unroll
    for (int nt = 0; nt < 4; ++nt)
#pragma unroll
      for (int kf = 0; kf < NKF; ++kf)
        bw[nt * NKF + kf] =
            *(const bf16x8*)&Wsrc[(size_t)(nt * 1024 + U + l15) * 1024 + k0 + kf * 32 + lh * 8];
  }
#pragma unroll
  for (int i = 0; i < 4 * NKF; ++i) asm volatile("" : "+v"(bw[i]));

  // elementwise cell: thread -> (batch b, unit j)
  int b = tid >> 4, j = tid & 15;
  int u = U + j;
  float bz0 = biasL[u], bz1 = biasL[1024 + u], bz2 = biasL[2048 + u], bz3 = biasL[3072 + u];
  float cst = 0.f;
  unsigned short* hhme = hh + (size_t)LAY * HD * HSLOT;
  const unsigned short* hhin = (LAY == 0) ? hhme : hh + (size_t)(LAY - 1) * HD * HSLOT;

  for (int s = 0; s < NSTEP; ++s) {
    int t = s - LAY;
    bool active = (t >= 0) && (t < T_);
    // ---- Zin prefetch (layer 0 only; overlaps the flag poll) ----
    unsigned short zv0 = 0, zv1 = 0, zv2 = 0, zv3 = 0;
    if (LAY == 0 && active) {
      const unsigned short* zr = Zin0 + (size_t)(b * T_ + t) * NG + u;
      zv0 = zr[0]; zv1 = zr[1024]; zv2 = zr[2048]; zv3 = zr[3072];
    }
    // ---- per-layer dependency wait ----
    if (s > 0) {
      if (kw == 0) {
        unsigned ss = (unsigned)s;
        const unsigned* fown = flags + LAY * 64 + lane;
        bool bp_on = (LAY < 2) && (s >= 32);
        unsigned bp = bp_on ? (unsigned)(s - 24) : 0u;
        for (;;) {
          bool ok = __hip_atomic_load(fown, __ATOMIC_RELAXED, __HIP_MEMORY_SCOPE_AGENT) >= ss;
          if constexpr (LAY > 0)
            ok &= __hip_atomic_load(flags + (LAY - 1) * 64 + lane, __ATOMIC_RELAXED,
                                    __HIP_MEMORY_SCOPE_AGENT) >= ss;
          if constexpr (LAY < 2) {
            if (bp_on)
              ok &= __hip_atomic_load(flags + (LAY + 1) * 64 + lane, __ATOMIC_RELAXED,
                                      __HIP_MEMORY_SCOPE_AGENT) >= bp;
          }
          if (__all(ok)) break;
          __builtin_amdgcn_s_sleep(1);
        }
        if ((s & (HD - 1)) == 0)
          __builtin_amdgcn_fence(__ATOMIC_ACQUIRE, "agent");  // clear caches before slot reuse
      }
      __syncthreads();
    }
    if (active) {
      // ---- GEMM: this wave's K-slice (unconditional; slot31 zeroed for t==0) ----
      const unsigned short* hsrc;
      if (LAY == 0)      hsrc = hhme + (size_t)((t - 1) & (HD - 1)) * HSLOT;
      else if (kw < 4)   hsrc = hhin + (size_t)(t & (HD - 1)) * HSLOT;
      else               hsrc = hhme + (size_t)((t - 1) & (HD - 1)) * HSLOT;
      f32x4 acc[2][4] = {};
#pragma unroll
      for (int kf = 0; kf < NKF; ++kf) {
        int k = (LAY == 0 ? kw * 128 : (kw & 3) * 256) + kf * 32 + lh * 8;
        const unsigned short* pa = hsrc + (k >> 2) * 128;
        u64 x0 = *(const u64*)(pa + l15 * 4);
        u64 x1 = *(const u64*)(pa + 128 + l15 * 4);
        u64 x2 = *(const u64*)(pa + 64 + l15 * 4);
        u64 x3 = *(const u64*)(pa + 192 + l15 * 4);
        bf16x8 a0, a1;
        ((u64*)&a0)[0] = x0; ((u64*)&a0)[1] = x1;
        ((u64*)&a1)[0] = x2; ((u64*)&a1)[1] = x3;
#pragma unroll
        for (int nt = 0; nt < 4; ++nt) {
          acc[0][nt] = __builtin_amdgcn_mfma_f32_16x16x32_bf16(a0, bw[nt * NKF + kf], acc[0][nt], 0, 0, 0);
          acc[1][nt] = __builtin_amdgcn_mfma_f32_16x16x32_bf16(a1, bw[nt * NKF + kf], acc[1][nt], 0, 0, 0);
        }
      }
      // ---- write split-K partials: zs[kw][mt*4+nt][lane][4] ----
#pragma unroll
      for (int mt = 0; mt < 2; ++mt)
#pragma unroll
        for (int nt = 0; nt < 4; ++nt)
          *(f32x4*)&zsb[(((kw * 8) + mt * 4 + nt) * 64 + lane) * 4] = acc[mt][nt];
    }
    __syncthreads();
    float hv = 0.f;   // kept for post-flag stores
    if (active) {
      // ---- reduce 8 partials + gates + state update ----
      int mt = b >> 4, lzs = ((b & 15) >> 2) * 16 + j, r = b & 3;
      float z0 = bz0, z1 = bz1, z2 = bz2, z3 = bz3;
#pragma unroll
      for (int k2 = 0; k2 < 8; ++k2) {
        int base = ((k2 * 8 + mt * 4) * 64 + lzs) * 4 + r;
        z0 += zsb[base];
        z1 += zsb[base + 256];
        z2 += zsb[base + 512];
        z3 += zsb[base + 768];
      }
      if (LAY == 0) { z0 += bf2f(zv0); z1 += bf2f(zv1); z2 += bf2f(zv2); z3 += bf2f(zv3); }
      float ig = sigm(z0), fg = sigm(z1), gg = tanh_(z2), og = sigm(z3);
      cst = fg * cst + ig * gg;
      hv = og * tanh_(cst);
      unsigned short hw = f2bf(hv);
      unsigned short* ha = hhme + (size_t)(t & (HD - 1)) * HSLOT + (u >> 2) * 128 + b * 4 + (u & 3);
      unsigned hw32 = hw;
      asm volatile("global_store_short %0, %1, off sc0 sc1" :: "v"(ha), "v"(hw32) : "memory");
    }
    // drain h-stores only (output stores are issued after the flag)
    asm volatile("s_waitcnt vmcnt(0)" ::: "memory");
    __syncthreads();
    if (tid == 0 && s < NSTEP - 1)
      __hip_atomic_store(&flags[LAY * 64 + wgl], (unsigned)(s + 1), __ATOMIC_RELAXED,
                         __HIP_MEMORY_SCOPE_AGENT);
    // ---- off-critical-path output stores ----
    if (active) {
      if (LAY == 2) __builtin_nontemporal_store(hv, &yout[(size_t)(b * T_ + t) * 1024 + u]);
      if (t == T_ - 1) {
        hT[LAY * (B_ * 1024) + b * 1024 + u] = hv;
        cT[LAY * (B_ * 1024) + b * 1024 + u] = cst;
      }
    }
  }
}

__global__ __launch_bounds__(512)
__attribute__((amdgpu_waves_per_eu(2, 2)))
void k_rec3(
    const unsigned short* __restrict__ WiT, const unsigned short* __restrict__ WhT,
    const unsigned short* __restrict__ Zin0, const float* __restrict__ bias,
    unsigned short* __restrict__ hh, unsigned int* __restrict__ flags,
    float* __restrict__ yout, float* __restrict__ hT, float* __restrict__ cT) {
  extern __shared__ float zsb[];   // 64KB: [kw][8][64][4] f32
  int wg = blockIdx.x;
  int lay = (wg >= 64) + (wg >= 128);
  int wgl = wg & 63;
  const unsigned short* WiL = WiT + (size_t)lay * NG * 1024;
  const unsigned short* WhL = WhT + (size_t)lay * NG * 1024;
  const float* biasL = bias + lay * NG;
  if (lay == 0)      rec_body<0>(WiL, WhL, Zin0, biasL, hh, flags, yout, hT, cT, wgl, zsb);
  else if (lay == 1) rec_body<1>(WiL, WhL, Zin0, biasL, hh, flags, yout, hT, cT, wgl, zsb);
  else               rec_body<2>(WiL, WhL, Zin0, biasL, hh, flags, yout, hT, cT, wgl, zsb);
}

extern "C" void kernel_launch(void* const* d_in, const int* in_sizes, int n_in,
                              void* d_out, int out_size, void* d_ws, size_t ws_size,
                              hipStream_t stream) {
  const float* x = (const float*)d_in[0];
  const float* Wi = (const float*)d_in[1];
  const float* Wh = (const float*)d_in[2];
  const float* bias = (const float*)d_in[3];
  float* out = (float*)d_out;
  uint8_t* W = (uint8_t*)d_ws;

  unsigned* flags = (unsigned*)W;                                   // 3 x 64 flags
  unsigned short* hh  = (unsigned short*)(W + 0x10000);             // 3 x 32 x 64KB = 6MB
  unsigned short* Zin0 = (unsigned short*)(W + 0x800000);           // 128MB bf16 (B*T,4096)
  unsigned short* Xa  = (unsigned short*)(W + 0x8800000);           // 32MB bf16 (B*T,1024)
  unsigned short* WiT = (unsigned short*)(W + 0xA800000);           // 24MB bf16 (L,4096,1024)
  unsigned short* WhT = (unsigned short*)(W + 0xC000000);           // 24MB (ends 0xD800000)

  hipMemsetAsync(d_ws, 0, 4096, stream);                            // flags
  // zero slot 31 of each layer's h-ring (read as h(-1)=0 at t==0)
  hipMemsetAsync(W + 0x10000 + (size_t)31 * 65536, 0, 65536, stream);
  hipMemsetAsync(W + 0x10000 + (size_t)63 * 65536, 0, 65536, stream);
  hipMemsetAsync(W + 0x10000 + (size_t)95 * 65536, 0, 65536, stream);
  k_conv<<<8192, 256, 0, stream>>>(x, Xa, (B_ * T_ * D_) / 8);
  k_transw<<<dim3(32, 128, 3), 256, 0, stream>>>(Wi, WiT);
  k_transw<<<dim3(32, 128, 3), 256, 0, stream>>>(Wh, WhT);
  k_gemm_in<<<4096, 256, 0, stream>>>(Xa, WiT, Zin0);   // layer 0 input gates

  float* yout = out;
  float* hT = out + 16777216;
  float* cT = out + 16777216 + 98304;
  k_rec3<<<NWG3, 512, 65536, stream>>>(WiT, WhT, Zin0, bias, hh, flags, yout, hT, cT);
}